// Round 8
// baseline (343.859 us; speedup 1.0000x reference)
//
#include <hip/hip_runtime.h>
#include <hip/hip_bf16.h>
#include <stdint.h>

using bf16 = __hip_bfloat16;

typedef __attribute__((ext_vector_type(8))) short short8;
typedef __attribute__((ext_vector_type(4))) float float4v;

namespace {
constexpr int kL  = 4096;
constexpr int kD  = 384;
constexpr int kGW = 64;
constexpr int kM  = 32768;
constexpr int kAP = 392;   // padded agg LDS stride (bf16): 784 B/row -> 2-way (free) banks

constexpr size_t nValue = (size_t)kM * kD;
constexpr size_t nW     = (size_t)kD * kD;
constexpr size_t nWcat  = (size_t)96 * kD;   // 96x384 (transposed cat weight)

// workspace offsets (bytes)
constexpr size_t oWvt  = 0;                                    // bf16 Wv^T [384][384]
constexpr size_t oWot  = oWvt  + nW * 2;                       // bf16 Wo^T [384][384]
constexpr size_t oWch  = oWot  + nW * 2;                       // bf16 Wcat^T hi [96][384]
constexpr size_t oWcl  = oWch  + nWcat * 2;                    // bf16 Wcat^T lo [96][384]
constexpr size_t oBcat = oWcl  + nWcat * 2;                    // f32 [96]
constexpr size_t oVB   = (oBcat + 96 * 4 + 255) & ~size_t(255);// bf16 v [kM][384]
constexpr size_t oProj = oVB   + nValue * 2;                   // f32 [kM][96]
}

__device__ __forceinline__ short bf16bits(float f) {
  bf16 h = __float2bfloat16(f);
  return *reinterpret_cast<short*>(&h);
}

__device__ __forceinline__ float bf16raw2f(unsigned short u) {
  union { unsigned int i; float f; } c;
  c.i = ((unsigned int)u) << 16;
  return c.f;
}

__device__ __forceinline__ short8 pack_hi8(const float4& f0, const float4& f1) {
  short8 hx;
  hx[0] = bf16bits(f0.x); hx[1] = bf16bits(f0.y);
  hx[2] = bf16bits(f0.z); hx[3] = bf16bits(f0.w);
  hx[4] = bf16bits(f1.x); hx[5] = bf16bits(f1.y);
  hx[6] = bf16bits(f1.z); hx[7] = bf16bits(f1.w);
  return hx;
}

__device__ __forceinline__ void pack_hilo8(const float4& f0, const float4& f1,
                                           short8& hx, short8& lx) {
  const float fv[8] = {f0.x, f0.y, f0.z, f0.w, f1.x, f1.y, f1.z, f1.w};
  #pragma unroll
  for (int q = 0; q < 8; ++q) {
    const bf16 h = __float2bfloat16(fv[q]);
    hx[q] = *reinterpret_cast<const short*>(&h);
    const bf16 lo = __float2bfloat16(fv[q] - __bfloat162float(h));
    lx[q] = *reinterpret_cast<const short*>(&lo);
  }
}

// -------------------------------------------------------------------------
// prep (weights only): Wv^T, Wo^T as bf16; Wcat^T split into hi/lo bf16 so
// the proj GEMM can run on MFMA with f32-level accuracy (err ~2^-17 rel).
// -------------------------------------------------------------------------
__global__ void prep_kernel(const float* __restrict__ Wv,
                            const float* __restrict__ Wo,
                            const float* __restrict__ Woff,
                            const float* __restrict__ Wwt,
                            const float* __restrict__ boff,
                            const float* __restrict__ bwt,
                            bf16* __restrict__ Wvt, bf16* __restrict__ Wot,
                            bf16* __restrict__ Wch, bf16* __restrict__ Wcl,
                            float* __restrict__ bcat)
{
  size_t i = (size_t)blockIdx.x * 256 + threadIdx.x;
  if (i < nW) {
    const int n = (int)(i / kD), k = (int)(i % kD);
    Wvt[i] = __float2bfloat16(Wv[(size_t)k * kD + n]);
    return;
  }
  i -= nW;
  if (i < nW) {
    const int n = (int)(i / kD), k = (int)(i % kD);
    Wot[i] = __float2bfloat16(Wo[(size_t)k * kD + n]);
    return;
  }
  i -= nW;
  if (i < nWcat) {
    const int n = (int)(i / kD), k = (int)(i % kD);
    const float val = (n < 64) ? Woff[(size_t)k * 64 + n] : Wwt[(size_t)k * 32 + (n - 64)];
    const bf16 h = __float2bfloat16(val);
    Wch[i] = h;
    Wcl[i] = __float2bfloat16(val - __bfloat162float(h));  // exact residual, then rounded
    return;
  }
  i -= nWcat;
  if (i < 96) bcat[i] = (i < 64) ? boff[i] : bwt[i - 64];
}

// -------------------------------------------------------------------------
// v GEMM, barrier-free streaming: vB[M,384] = value @ Wv + bv, bf16 out.
// Every schedule with a per-K-step __syncthreads plateaued at 63-72 us
// (r1/r2/r4/r5/r7) because its implicit vmcnt(0) drains the whole load
// queue 12x/block. Here: NO LDS, NO barriers. Each wave owns a private
// 16x64 sub-tile; A-frags load f32 direct from global into depth-2 named
// register slots (kt&1 under full unroll -> constant idx, rule #20);
// B-frags load direct from L2 (Wvt 288 KB hot). Next-kt loads issue
// BEFORE current MFMAs, so the compiler's counted vmcnt keeps ~12 loads
// in flight and never drains. Same rounding + per-acc order -> bitwise-
// identical vB.
// Block = 4 waves x 16 rows = 64 rows x 64 cols. Grid v = 512*6 = 3072.
// -------------------------------------------------------------------------
__device__ __forceinline__
void vgemm_free(int bid, const float* __restrict__ A, const bf16* __restrict__ Bt,
                const float* __restrict__ bias, bf16* __restrict__ Cout)
{
  const int lane = threadIdx.x & 63;
  const int wave = threadIdx.x >> 6;
  const int bm = bid / 6, bn = bid % 6;
  const int m0 = bm * 64 + wave * 16;      // wave-private 16 rows
  const int n0 = bn * 64;
  const int r16 = lane & 15, quad = lane >> 4;

  const float* Ab = A  + (size_t)(m0 + r16) * kD + quad * 8;
  const bf16*  Bb = Bt + (size_t)(n0 + r16) * kD + quad * 8;

  float4v acc[4];
  #pragma unroll
  for (int j = 0; j < 4; ++j) acc[j] = (float4v){0.f, 0.f, 0.f, 0.f};

  float4 fa[2][2];
  short8 bv[2][4];

  // prologue: kt=0 into slot 0
  fa[0][0] = *(const float4*)(Ab);
  fa[0][1] = *(const float4*)(Ab + 4);
  #pragma unroll
  for (int j = 0; j < 4; ++j)
    bv[0][j] = *(const short8*)(Bb + (size_t)(j * 16) * kD);

  #pragma unroll
  for (int kt = 0; kt < 12; ++kt) {
    const int cur = kt & 1, nxt = cur ^ 1;
    if (kt < 11) {
      const int k1 = (kt + 1) * 32;
      #pragma unroll
      for (int j = 0; j < 4; ++j)
        bv[nxt][j] = *(const short8*)(Bb + (size_t)(j * 16) * kD + k1);
      fa[nxt][0] = *(const float4*)(Ab + k1);
      fa[nxt][1] = *(const float4*)(Ab + k1 + 4);
    }
    const short8 av = pack_hi8(fa[cur][0], fa[cur][1]);
    #pragma unroll
    for (int j = 0; j < 4; ++j)
      acc[j] = __builtin_amdgcn_mfma_f32_16x16x32_bf16(av, bv[cur][j], acc[j], 0, 0, 0);
  }

  #pragma unroll
  for (int j = 0; j < 4; ++j) {
    const int col = n0 + j * 16 + r16;
    const float bj = bias[col];
    const int mb = m0 + quad * 4;
    #pragma unroll
    for (int r = 0; r < 4; ++r)
      Cout[(size_t)(mb + r) * kD + col] = __float2bfloat16(acc[j][r] + bj);
  }
}

// -------------------------------------------------------------------------
// proj GEMM, barrier-free streaming split-bf16 MFMA:
// proj[M,96] = Q @ Wcat + bcat, acc = Ahi*Bhi + Ahi*Blo + Alo*Bhi.
// Wave-private 32x48 sub-tile; A f32 direct->reg depth-2 (hi/lo cvt at
// use); B hi/lo direct from L2 at loop top (issued before A-prefetch so
// the MFMA wait leaves A in flight). No LDS, no barriers. Accumulation
// order matches r7 (j-outer, i-inner, hh/hl/lh) -> bitwise-same proj.
// Block = 4 waves: (wave>>1) row-half, (wave&1) col-half. Grid = 512.
// -------------------------------------------------------------------------
__device__ __forceinline__
void proj_free(int bid, const float* __restrict__ Q,
               const bf16* __restrict__ WhT, const bf16* __restrict__ WlT,
               const float* __restrict__ bc, float* __restrict__ proj)
{
  const int lane = threadIdx.x & 63;
  const int wave = threadIdx.x >> 6;
  const int m0 = bid * 64 + (wave >> 1) * 32;   // wave's 32 rows
  const int wn = (wave & 1) * 48;
  const int r16 = lane & 15, quad = lane >> 4;

  const float* Ab  = Q   + (size_t)(m0 + r16) * kD + quad * 8;
  const bf16*  Bhb = WhT + (size_t)(wn + r16) * kD + quad * 8;
  const bf16*  Blb = WlT + (size_t)(wn + r16) * kD + quad * 8;

  float4v acc[2][3];
  #pragma unroll
  for (int i = 0; i < 2; ++i)
    #pragma unroll
    for (int j = 0; j < 3; ++j) acc[i][j] = (float4v){0.f, 0.f, 0.f, 0.f};

  float4 fa[2][2][2];   // [slot][frag i][half]
  #pragma unroll
  for (int i = 0; i < 2; ++i) {
    fa[0][i][0] = *(const float4*)(Ab + (size_t)(i * 16) * kD);
    fa[0][i][1] = *(const float4*)(Ab + (size_t)(i * 16) * kD + 4);
  }

  #pragma unroll
  for (int kt = 0; kt < 12; ++kt) {
    const int cur = kt & 1, nxt = cur ^ 1;
    const int k0 = kt * 32;
    // B (L2-hot) issued first so the MFMA wait keeps A-prefetch in flight
    short8 bvh[3], bvl[3];
    #pragma unroll
    for (int j = 0; j < 3; ++j) {
      bvh[j] = *(const short8*)(Bhb + (size_t)(j * 16) * kD + k0);
      bvl[j] = *(const short8*)(Blb + (size_t)(j * 16) * kD + k0);
    }
    if (kt < 11) {
      const int k1 = k0 + 32;
      #pragma unroll
      for (int i = 0; i < 2; ++i) {
        fa[nxt][i][0] = *(const float4*)(Ab + (size_t)(i * 16) * kD + k1);
        fa[nxt][i][1] = *(const float4*)(Ab + (size_t)(i * 16) * kD + k1 + 4);
      }
    }
    short8 avh[2], avl[2];
    #pragma unroll
    for (int i = 0; i < 2; ++i)
      pack_hilo8(fa[cur][i][0], fa[cur][i][1], avh[i], avl[i]);
    #pragma unroll
    for (int j = 0; j < 3; ++j)
      #pragma unroll
      for (int i = 0; i < 2; ++i) {
        acc[i][j] = __builtin_amdgcn_mfma_f32_16x16x32_bf16(avh[i], bvh[j], acc[i][j], 0, 0, 0);
        acc[i][j] = __builtin_amdgcn_mfma_f32_16x16x32_bf16(avh[i], bvl[j], acc[i][j], 0, 0, 0);
        acc[i][j] = __builtin_amdgcn_mfma_f32_16x16x32_bf16(avl[i], bvh[j], acc[i][j], 0, 0, 0);
      }
  }

  #pragma unroll
  for (int j = 0; j < 3; ++j) {
    const int col = wn + j * 16 + r16;
    const float bj = bc[col];
    #pragma unroll
    for (int i = 0; i < 2; ++i) {
      const int mb = m0 + i * 16 + quad * 4;
      #pragma unroll
      for (int r = 0; r < 4; ++r)
        proj[(size_t)(mb + r) * 96 + col] = acc[i][j][r] + bj;
    }
  }
}

// -------------------------------------------------------------------------
// Fat kernel: blocks [0,512) proj (64-row tiles), [512,3584) v GEMM
// (64x64 tiles). ZERO LDS, zero barriers -> occupancy purely VGPR-bound;
// waves are independent streams with compiler-counted vmcnt.
// v-segment XCD swizzle: ld = (vb&7)*384 + vb>>3 -> each XCD owns one
// batch's rows AND all 6 col-blocks of a row-chunk dispatch consecutively
// (A re-reads L2-hit; r7 verified FETCH halves with this mapping).
// -------------------------------------------------------------------------
__global__ __launch_bounds__(256)
void fat_kernel(const float* __restrict__ value, const bf16* __restrict__ Wvt,
                const float* __restrict__ bv,    bf16* __restrict__ vB,
                const float* __restrict__ Q,     const bf16* __restrict__ Wch,
                const bf16* __restrict__ Wcl,    const float* __restrict__ bcat,
                float* __restrict__ proj)
{
  const int pb = blockIdx.x;
  if (pb < 512) {
    proj_free(pb, Q, Wch, Wcl, bcat, proj);
  } else {
    const int vb = pb - 512;                   // 0..3071
    const int ld = (vb & 7) * 384 + (vb >> 3); // XCD-chunked, bijective
    vgemm_free(ld, value, Wvt, bv, vB);
  }
}

// -------------------------------------------------------------------------
// tail kernel: fused sample + output GEMM (unchanged from r7 — proven,
// and tail-side deltas have never moved the total). 512 blocks x 512 thr.
// -------------------------------------------------------------------------
__global__ __launch_bounds__(512)
void tail_kernel(const float* __restrict__ proj, const bf16* __restrict__ v,
                 const bf16* __restrict__ Wot, const float* __restrict__ bo,
                 float* __restrict__ out)
{
  __shared__ __align__(16) char smem[66560];
  bf16*   sAgg  = (bf16*)smem;                 // [64][392] = 50176 B
  int4*   scoff = (int4*)(smem + 50176);       // [512] = 8192 B
  float4* scw   = (float4*)(smem + 58368);     // [512] = 8192 B

  const int raw   = blockIdx.x;
  const int chunk = (raw & 7) * 64 + (raw >> 3);
  const int m0    = chunk * 64;
  const int b     = m0 >> 12;
  const int l0    = m0 & 4095;
  const int t     = threadIdx.x;

  // ---------------- phase 1: sample ----------------
  for (int ct = 0; ct < 4; ++ct) {
    const int tok0 = ct * 16;
    {
      const int tl = t >> 5, pt = t & 31;      // 16 tok x 32 pts, 1/thread
      const int tok = tok0 + tl;
      const int l   = l0 + tok;
      const float* pb_ = proj + (size_t)(m0 + tok) * 96;
      const float2 off = *(const float2*)(pb_ + 2 * pt);
      const int h = pt >> 2, p = pt & 3;
      const float4 lg = *(const float4*)(pb_ + 64 + h * 4);
      const float g[4] = {lg.x, lg.y, lg.z, lg.w};
      const float mx = fmaxf(fmaxf(g[0], g[1]), fmaxf(g[2], g[3]));
      float e[4], sum = 0.f;
      #pragma unroll
      for (int jj = 0; jj < 4; ++jj) { e[jj] = expf(g[jj] - mx); sum += e[jj]; }
      const float wt = e[p] / sum;
      const float refx = (float)(l & 63) * (1.0f / 63.0f);
      const float refy = (float)(l >> 6) * (1.0f / 63.0f);
      const float locx = fminf(fmaxf(refx + off.x, 0.f), 1.f);
      const float locy = fminf(fmaxf(refy + off.y, 0.f), 1.f);
      const float ph = locx * 63.0f;           // faithful: component 0 -> row coord
      const float pw = locy * 63.0f;
      const float fy = floorf(ph), fx = floorf(pw);
      const int y0 = (int)fy, x0 = (int)fx;
      const int y1 = min(y0 + 1, 63), x1 = min(x0 + 1, 63);
      const float wy = ph - fy, wx = pw - fx;
      scoff[tl * 32 + pt] = make_int4((y0 * kGW + x0) * kD, (y0 * kGW + x1) * kD,
                                      (y1 * kGW + x0) * kD, (y1 * kGW + x1) * kD);
      scw[tl * 32 + pt] = make_float4(wt * (1.f - wy) * (1.f - wx), wt * (1.f - wy) * wx,
                                      wt * wy * (1.f - wx),         wt * wy * wx);
    }
    __syncthreads();
    // gather: 768 tasks = 16 tok x 48 groups of 8 dims, 16 B loads
    #pragma unroll
    for (int it = 0; it < 2; ++it) {
      const int task = t + it * 512;           // 0..1023, valid < 768
      if (task < 768) {
        const int tl = task / 48;
        const int g  = task - tl * 48;
        const int h  = g / 6;                  // 6 groups per head (48 dims)
        const int col = g * 8;
        const bf16* vb = v + (size_t)b * kL * kD + col;
        float av[8] = {0.f, 0.f, 0.f, 0.f, 0.f, 0.f, 0.f, 0.f};
        #pragma unroll
        for (int p = 0; p < 4; ++p) {
          const int4   o = scoff[tl * 32 + h * 4 + p];
          const float4 w = scw  [tl * 32 + h * 4 + p];
          const short8 u0 = *(const short8*)(vb + o.x);
          const short8 u1 = *(const short8*)(vb + o.y);
          const short8 u2 = *(const short8*)(vb + o.z);
          const short8 u3 = *(const short8*)(vb + o.w);
          #pragma unroll
          for (int d = 0; d < 8; ++d) {
            av[d] += w.x * bf16raw2f((unsigned short)u0[d])
                   + w.y * bf16raw2f((unsigned short)u1[d])
                   + w.z * bf16raw2f((unsigned short)u2[d])
                   + w.w * bf16raw2f((unsigned short)u3[d]);
          }
        }
        short8 ou;
        #pragma unroll
        for (int d = 0; d < 8; ++d) ou[d] = bf16bits(av[d]);
        *(short8*)(sAgg + (size_t)(tok0 + tl) * kAP + col) = ou;
      }
    }
    __syncthreads();   // gather done; scratch reusable / sAgg rows published
  }

  // ---------------- phase 2: out = sAgg @ Wo^T + bo (no barriers) --------
  const int lane = t & 63, wave = t >> 6;
  const int r16 = lane & 15, quad = lane >> 4;
  const int wn = wave * 48;                    // 8 waves x 48 cols = 384
  float4v acc2[4][3];
  #pragma unroll
  for (int i = 0; i < 4; ++i)
    #pragma unroll
    for (int j = 0; j < 3; ++j) acc2[i][j] = (float4v){0.f, 0.f, 0.f, 0.f};

  const bf16* Bbase = Wot + (size_t)(wn + r16) * kD + quad * 8;

  #pragma unroll
  for (int kt = 0; kt < 12; ++kt) {
    const int k0 = kt * 32;
    short8 av[4];
    #pragma unroll
    for (int i = 0; i < 4; ++i)
      av[i] = *(const short8*)(sAgg + (size_t)(i * 16 + r16) * kAP + k0 + quad * 8);
    #pragma unroll
    for (int j = 0; j < 3; ++j) {
      const short8 bvj = *(const short8*)(Bbase + (size_t)(j * 16) * kD + k0);
      #pragma unroll
      for (int i = 0; i < 4; ++i)
        acc2[i][j] = __builtin_amdgcn_mfma_f32_16x16x32_bf16(av[i], bvj, acc2[i][j], 0, 0, 0);
    }
  }

  #pragma unroll
  for (int j = 0; j < 3; ++j) {
    const int col = wn + j * 16 + r16;
    const float bj = bo[col];
    #pragma unroll
    for (int i = 0; i < 4; ++i) {
      const int mb = m0 + i * 16 + quad * 4;
      #pragma unroll
      for (int r = 0; r < 4; ++r)
        out[(size_t)(mb + r) * kD + col] = acc2[i][j][r] + bj;
    }
  }
}

extern "C" void kernel_launch(void* const* d_in, const int* in_sizes, int n_in,
                              void* d_out, int out_size, void* d_ws, size_t ws_size,
                              hipStream_t stream)
{
  const float* query = (const float*)d_in[0];
  const float* value = (const float*)d_in[2];
  const float* Wv    = (const float*)d_in[7];
  const float* bv    = (const float*)d_in[8];
  const float* Woff  = (const float*)d_in[9];
  const float* boff  = (const float*)d_in[10];
  const float* Wwt   = (const float*)d_in[11];
  const float* bwt   = (const float*)d_in[12];
  const float* Wo    = (const float*)d_in[13];
  const float* bo    = (const float*)d_in[14];
  float* out = (float*)d_out;

  char* ws = (char*)d_ws;
  bf16*  Wvt  = (bf16*)(ws + oWvt);
  bf16*  Wot  = (bf16*)(ws + oWot);
  bf16*  Wch  = (bf16*)(ws + oWch);
  bf16*  Wcl  = (bf16*)(ws + oWcl);
  float* bcat = (float*)(ws + oBcat);
  bf16*  vB   = (bf16*)(ws + oVB);
  float* proj = (float*)(ws + oProj);

  const size_t prepN = nW + nW + nWcat + 96;
  prep_kernel<<<dim3((unsigned)((prepN + 255) / 256)), 256, 0, stream>>>(
      Wv, Wo, Woff, Wwt, boff, bwt, Wvt, Wot, Wch, Wcl, bcat);

  // proj (512 blocks) + vGEMM (3072 blocks), barrier-free reg-streaming
  fat_kernel<<<dim3(512 + 3072), 256, 0, stream>>>(
      value, Wvt, bv, vB, query, Wch, Wcl, bcat, proj);

  // fused: coords + softmax + bilinear gather (16B loads) -> out GEMM
  tail_kernel<<<dim3(512), 512, 0, stream>>>(proj, vB, Wot, bo, out);
}